// Round 10
// baseline (66.332 us; speedup 1.0000x reference)
//
#include <hip/hip_runtime.h>
#include <stdint.h>

#define H 128
#define W 128
#define CIN 64
#define COUT 64
#define NB 8
#define WR 4        // pixel rows per block
#define WC 16       // pixel cols per block
#define CW 20       // staged cols per window row (WC+4)
#define PLANE 162   // slots per chunk-plane; 162 % 8 == 2 -> quarter decorrelation
#define REDS 260    // reduction scratch row stride (floats)

typedef __attribute__((ext_vector_type(4))) float f32x4;
typedef __attribute__((ext_vector_type(2))) _Float16 f16x2;
typedef __attribute__((ext_vector_type(8))) _Float16 f16x8;
typedef __attribute__((ext_vector_type(4))) unsigned int u32x4;
typedef __attribute__((ext_vector_type(2))) unsigned int u32x2;

__device__ __forceinline__ f16x2 bch2(unsigned u) { return __builtin_bit_cast(f16x2, u); }
__device__ __forceinline__ unsigned bcu(f16x2 v) { return __builtin_bit_cast(unsigned, v); }

// ---- kernel 0: x NCHW f32 -> NHWC f16 (xt[b][h][w][c]) via LDS tile transpose
__global__ __launch_bounds__(256) void x_to_nhwc(const float* __restrict__ x,
                                                 _Float16* __restrict__ xt) {
    __shared__ _Float16 tile[W][68];
    int bh = blockIdx.x;
    int h = bh & (H - 1), b = bh >> 7;
    int t = threadIdx.x;
    #pragma unroll
    for (int i = 0; i < 8; ++i) {
        int idx = i * 256 + t;
        int c = idx >> 5;
        int w4 = (idx & 31) << 2;
        f32x4 v = *(const f32x4*)(x + (((size_t)(b * CIN + c) * H + h) * W + w4));
        #pragma unroll
        for (int j = 0; j < 4; ++j) tile[w4 + j][c] = (_Float16)v[j];
    }
    __syncthreads();
    _Float16* dst = xt + (size_t)bh * W * CIN;
    #pragma unroll
    for (int i = 0; i < 8; ++i) {
        int idx = i * 256 + t;
        int w = idx >> 4;
        int c4 = (idx & 15) << 2;
        *(uint2*)(dst + (size_t)w * CIN + c4) = *(const uint2*)&tile[w][c4];
    }
}

// ---- kernel 1: prepack weights, MFMA-lane-coalesced layout
__global__ __launch_bounds__(256) void prep_w(const float* __restrict__ wo,
                                              const float* __restrict__ wc,
                                              _Float16* __restrict__ wao2,
                                              _Float16* __restrict__ wac2) {
    int t = blockIdx.x * 256 + threadIdx.x;
    if (t < 18432) {
        int j = t & 7, l = (t >> 3) & 63, m = (t >> 9) & 1, kk = t >> 10;
        int cout = m * 16 + (l & 15);
        int cin = (kk & 1) * 32 + ((l >> 4) << 3) + j;
        wao2[t] = (cout < 18) ? (_Float16)wo[(cout * 64 + cin) * 9 + (kk >> 1)]
                              : (_Float16)0.f;
    } else if (t < 18432 + 36864) {
        int u = t - 18432;
        int j = u & 7, l = (u >> 3) & 63, m = (u >> 9) & 3, kk = u >> 11;
        int cout = m * 16 + (l & 15);
        int cin = (kk & 1) * 32 + ((l >> 4) << 3) + j;
        wac2[u] = (_Float16)wc[(cout * 64 + cin) * 9 + (kk >> 1)];
    }
}

// ---- kernel 2: fused offset-conv + coord setup + deformable conv.
// 512 threads = 8 waves, wave-pair K-split. Phase-C metadata is ZERO-DECODE:
// M0 = 4 ready byte-offsets (oow flag bit0; global offsets when oow),
// M1 = 4 pre-duplicated f16x2 bilinear weights.
__global__ __launch_bounds__(512, 4) void deform_fused(const _Float16* __restrict__ xt,
                                                       const _Float16* __restrict__ wao2,
                                                       const _Float16* __restrict__ wac2,
                                                       const float* __restrict__ bo,
                                                       const float* __restrict__ bconv,
                                                       float* __restrict__ out) {
    __shared__ u32x4 s_x[8 * PLANE];     // 20.7 KB chunk-planes
    __shared__ u32x4 s_m0[4][144];       // byte offsets  (9.2 KB) (also phase-A scratch)
    __shared__ u32x4 s_m1[4][144];       // dup weights   (9.2 KB)

    int bid = blockIdx.x;
    int b = bid & 7;                      // XCD swizzle: XCD k <- batch k
    int r = bid >> 3;
    int h0 = ((r >> 3) & 31) << 2;
    int w0 = (r & 7) << 4;

    int r_lo = max(0, h0 - 2), r_hi = min(H - 1, h0 + 5);
    int c_lo = max(0, w0 - 2), c_hi = min(W - 1, w0 + WC + 1);
    int nr = r_hi - r_lo + 1, nc = c_hi - c_lo + 1;

    int t = threadIdx.x;
    int lane = t & 63, wv = t >> 6;
    int g = wv & 3;                       // pixel row within tile
    int half = wv >> 2;                   // 0: ch 0..31, 1: ch 32..63
    int pcol = lane & 15, hq = lane >> 4;
    int pl = half * 4 + hq;               // this lane's channel chunk (8 ch)
    int h = h0 + g;
    int wp = w0 + pcol;

    const _Float16* xb = xt + (size_t)b * H * W * CIN;

    // ---------- stage x window into LDS chunk-planes ----------
    {
        int cs = t >> 3, ch = t & 7;
        bool act = t < nc * 8;
        for (int rr = 0; rr < nr; ++rr) {
            if (act) {
                u32x4 v = *(const u32x4*)(xb + (size_t)((r_lo + rr) * W + c_lo + cs) * CIN + (ch << 3));
                s_x[ch * PLANE + rr * CW + cs] = v;
            }
        }
    }
    __syncthreads();

    const u32x4* sp = s_x + pl * PLANE;

    // ---------- phase A: offset conv via MFMA (this wave's channel half) ----------
    f32x4 ao0 = {}, ao1 = {};
    #pragma unroll
    for (int k = 0; k < 9; ++k) {
        int yy = h + k / 3 - 1;
        int xx = wp + k % 3 - 1;
        bool valid = ((unsigned)yy < (unsigned)H) && ((unsigned)xx < (unsigned)W);
        int yc = min(max(yy, 0), H - 1);
        int xc = min(max(xx, 0), W - 1);
        int s = (yc - r_lo) * CW + (xc - c_lo);
        u32x4 v = sp[s];
        u32x4 z = {};
        if (!valid) v = z;
        f16x8 bf = __builtin_bit_cast(f16x8, v);
        const _Float16* wb = wao2 + (size_t)(4 * k + 2 * half) * 512 + lane * 8;
        ao0 = __builtin_amdgcn_mfma_f32_16x16x32_f16(*(const f16x8*)(wb), bf, ao0, 0, 0, 0);
        ao1 = __builtin_amdgcn_mfma_f32_16x16x32_f16(*(const f16x8*)(wb + 512), bf, ao1, 0, 0, 0);
    }

    // ---------- reduce phase-A partials (odd half -> LDS -> even half) ----------
    if (half == 1) {
        float* sc = (float*)&s_m0[g][0] + lane * 6;
        sc[0] = ao0[0]; sc[1] = ao0[1]; sc[2] = ao0[2]; sc[3] = ao0[3];
        sc[4] = ao1[0]; sc[5] = ao1[1];
    }
    __syncthreads();

    if (half == 0) {
        // read partner's partials FIRST (lockstep: reads issue before aliased writes)
        const float* sc = (const float*)&s_m0[g][0] + lane * 6;
        float p0 = sc[0], p1 = sc[1], p2 = sc[2], p3 = sc[3], p4 = sc[4], p5 = sc[5];
        ao0[0] += p0; ao0[1] += p1; ao0[2] += p2; ao0[3] += p3;
        ao1[0] += p4; ao1[1] += p5;

        auto setup = [&](int k, float dy, float dx) {
            float py = (float)(h + k / 3 - 1) + dy;
            float px = (float)(wp + k % 3 - 1) + dx;
            float y0f = floorf(py), x0f = floorf(px);
            float fy = py - y0f, fx = px - x0f;
            float vy0 = (y0f >= 0.f  && y0f <= 127.f) ? 1.f : 0.f;
            float vy1 = (y0f >= -1.f && y0f <= 126.f) ? 1.f : 0.f;
            float vx0 = (x0f >= 0.f  && x0f <= 127.f) ? 1.f : 0.f;
            float vx1 = (x0f >= -1.f && x0f <= 126.f) ? 1.f : 0.f;
            float g0 = (1.f - fy) * (1.f - fx) * vy0 * vx0;
            float g1 = (1.f - fy) * fx         * vy0 * vx1;
            float g2 = fy * (1.f - fx)         * vy1 * vx0;
            float g3 = fy * fx                 * vy1 * vx1;
            int y0i = (int)fminf(fmaxf(y0f, 0.f), 127.f);
            int x0i = (int)fminf(fmaxf(x0f, 0.f), 127.f);
            int y1i = (int)fminf(fmaxf(y0f + 1.f, 0.f), 127.f);
            int x1i = (int)fminf(fmaxf(x0f + 1.f, 0.f), 127.f);
            bool inw = (y0i >= r_lo) && (y1i <= r_hi) && (x0i >= c_lo) && (x1i <= c_hi);
            u32x4 m0;
            if (inw) {
                unsigned s00 = (unsigned)((y0i - r_lo) * CW + (x0i - c_lo));
                unsigned dxb = (unsigned)(x1i - x0i);
                unsigned dyb = (unsigned)(y1i - y0i);
                m0[0] = s00 * 16u;
                m0[1] = (s00 + dxb) * 16u;
                m0[2] = (s00 + dyb * CW) * 16u;
                m0[3] = (s00 + dyb * CW + dxb) * 16u;
            } else {
                m0[0] = ((unsigned)(y0i * W + x0i) * 128u) | 1u;
                m0[1] = (unsigned)(y0i * W + x1i) * 128u;
                m0[2] = (unsigned)(y1i * W + x0i) * 128u;
                m0[3] = (unsigned)(y1i * W + x1i) * 128u;
            }
            u32x4 m1;
            m1[0] = bcu((f16x2){(_Float16)g0, (_Float16)g0});
            m1[1] = bcu((f16x2){(_Float16)g1, (_Float16)g1});
            m1[2] = bcu((f16x2){(_Float16)g2, (_Float16)g2});
            m1[3] = bcu((f16x2){(_Float16)g3, (_Float16)g3});
            s_m0[g][k * 16 + pcol] = m0;
            s_m1[g][k * 16 + pcol] = m1;
        };
        f32x4 bo4 = *(const f32x4*)(bo + 4 * hq);
        setup(2 * hq,     ao0[0] + bo4[0], ao0[1] + bo4[1]);
        setup(2 * hq + 1, ao0[2] + bo4[2], ao0[3] + bo4[3]);
        if (hq == 0) setup(8, ao1[0] + bo[16], ao1[1] + bo[17]);
    }
    __syncthreads();

    // ---------- phase C: deformable conv, zero-decode metadata ----------
    const char* lb = (const char*)s_x + pl * (PLANE * 16);
    const char* gb = (const char*)xb + (pl << 4);
    f32x4 acc[4] = {};

    #pragma unroll
    for (int k = 0; k < 9; ++k) {
        u32x4 m0 = s_m0[g][k * 16 + pcol];
        u32x4 m1 = s_m1[g][k * 16 + pcol];
        u32x4 c00 = *(const u32x4*)(lb + (m0[0] & 0xFFFFFFFEu));
        u32x4 c01 = *(const u32x4*)(lb + m0[1]);
        u32x4 c10 = *(const u32x4*)(lb + m0[2]);
        u32x4 c11 = *(const u32x4*)(lb + m0[3]);
        if (__builtin_expect((m0[0] & 1u) != 0u, 0)) {   // rare far-offset fallback
            c00 = *(const u32x4*)(gb + (m0[0] & 0xFFFFFFFEu));
            c01 = *(const u32x4*)(gb + m0[1]);
            c10 = *(const u32x4*)(gb + m0[2]);
            c11 = *(const u32x4*)(gb + m0[3]);
        }
        f16x2 w00d = bch2(m1[0]), w01d = bch2(m1[1]);
        f16x2 w10d = bch2(m1[2]), w11d = bch2(m1[3]);
        u32x4 fr;
        #pragma unroll
        for (int d = 0; d < 4; ++d) {
            f16x2 v = bch2(c00[d]) * w00d + bch2(c01[d]) * w01d
                    + bch2(c10[d]) * w10d + bch2(c11[d]) * w11d;
            fr[d] = bcu(v);
        }
        f16x8 bf = __builtin_bit_cast(f16x8, fr);
        const _Float16* ab = wac2 + (size_t)(8 * k + 4 * half) * 512 + lane * 8;
        __builtin_amdgcn_s_setprio(1);
        #pragma unroll
        for (int m = 0; m < 4; ++m)
            acc[m] = __builtin_amdgcn_mfma_f32_16x16x32_f16(*(const f16x8*)(ab + m * 512), bf, acc[m], 0, 0, 0);
        __builtin_amdgcn_s_setprio(0);
    }

    // ---------- reduce phase-C partials through s_x (dead now) ----------
    __syncthreads();                      // all s_x corner reads complete
    float* red = (float*)s_x;             // [16][REDS] transposed: conflict-free b32
    if (half == 0) {
        #pragma unroll
        for (int m = 0; m < 4; ++m)
            #pragma unroll
            for (int r2 = 0; r2 < 4; ++r2)
                red[(m * 4 + r2) * REDS + g * 64 + lane] = acc[m][r2];
    }
    __syncthreads();
    if (half == 1) {
        #pragma unroll
        for (int m = 0; m < 4; ++m) {
            f32x4 bc4 = *(const f32x4*)(bconv + m * 16 + (hq << 2));
            #pragma unroll
            for (int r2 = 0; r2 < 4; ++r2) {
                int co = (m << 4) + (hq << 2) + r2;
                float v = acc[m][r2] + red[(m * 4 + r2) * REDS + g * 64 + lane] + bc4[r2];
                out[(((size_t)b * COUT + co) * H + h) * W + wp] = v;
            }
        }
    }
}

extern "C" void kernel_launch(void* const* d_in, const int* in_sizes, int n_in,
                              void* d_out, int out_size, void* d_ws, size_t ws_size,
                              hipStream_t stream) {
    const float* x  = (const float*)d_in[0];
    const float* wo = (const float*)d_in[1];
    const float* bo = (const float*)d_in[2];
    const float* wc = (const float*)d_in[3];
    const float* bc = (const float*)d_in[4];
    float* out = (float*)d_out;

    _Float16* xt   = (_Float16*)d_ws;                                   // 16.78 MB
    _Float16* wao2 = (_Float16*)((char*)d_ws + (size_t)NB * H * W * CIN * 2);
    _Float16* wac2 = wao2 + 18432;

    x_to_nhwc<<<NB * H, 256, 0, stream>>>(x, xt);
    prep_w<<<(18432 + 36864 + 255) / 256, 256, 0, stream>>>(wo, wc, wao2, wac2);
    deform_fused<<<NB * H * W / (WR * WC), 512, 0, stream>>>(xt, wao2, wac2, bo, bc, out);
}